// Round 8
// baseline (70.538 us; speedup 1.0000x reference)
//
#include <hip/hip_runtime.h>
#include <math.h>

#define T_SEQ 2048

typedef float  fx4 __attribute__((ext_vector_type(4)));
typedef short  sx4 __attribute__((ext_vector_type(4)));
typedef short  sx8 __attribute__((ext_vector_type(8)));
typedef unsigned short u16;

static __device__ __forceinline__ u16 f2b(float f) {
  unsigned u = __builtin_bit_cast(unsigned, f);
  u += 0x7fffu + ((u >> 16) & 1u);   // RNE
  return (u16)(u >> 16);
}
static __device__ __forceinline__ float b2f(u16 v) {
  unsigned u = ((unsigned)v) << 16;
  return __builtin_bit_cast(float, u);
}

static __device__ __forceinline__ fx4 mfma16(sx4 a, sx4 b, fx4 c) {
  return __builtin_amdgcn_mfma_f32_16x16x16bf16_1k(a, b, c, 0, 0, 0);
}
static __device__ __forceinline__ fx4 mfma32(sx8 a, sx8 b, fx4 c) {
  return __builtin_amdgcn_mfma_f32_16x16x32_bf16(a, b, c, 0, 0, 0);
}

static __device__ __forceinline__ void gload16(const void* g, void* l) {
  __builtin_amdgcn_global_load_lds(
      (const __attribute__((address_space(1))) unsigned*)g,
      (__attribute__((address_space(3))) unsigned*)l, 16, 0, 0);
}

// -- prep: LN1 + x->bf16 (blocks 0..2047), weight transposes (2048..2815) ----
__global__ __launch_bounds__(256) void prep_k(
    const float* __restrict__ x, const float* __restrict__ g1,
    const float* __restrict__ b1, u16* __restrict__ xn, u16* __restrict__ xb,
    const float* __restrict__ ipw, const float* __restrict__ outw,
    const float* __restrict__ w1, const float* __restrict__ w2,
    u16* __restrict__ ipwT, u16* __restrict__ outwT,
    u16* __restrict__ w1T, u16* __restrict__ w2T) {
  const int bid = blockIdx.x;
  if (bid < 2048) {
    const int row = bid * 4 + (threadIdx.x >> 6);
    const int l = threadIdx.x & 63;
    fx4 v = *(const fx4*)&x[(size_t)row * 256 + l * 4];
    float s = v.x + v.y + v.z + v.w;
    float q = v.x * v.x + v.y * v.y + v.z * v.z + v.w * v.w;
#pragma unroll
    for (int off = 1; off < 64; off <<= 1) {
      s += __shfl_xor(s, off);
      q += __shfl_xor(q, off);
    }
    const float mean = s * (1.0f / 256.0f);
    const float var = q * (1.0f / 256.0f) - mean * mean;
    const float rstd = rsqrtf(var + 1e-5f);
    fx4 gv = *(const fx4*)&g1[l * 4];
    fx4 bv = *(const fx4*)&b1[l * 4];
    sx4 o, xo;
    o[0] = (short)f2b((v.x - mean) * rstd * gv.x + bv.x);
    o[1] = (short)f2b((v.y - mean) * rstd * gv.y + bv.y);
    o[2] = (short)f2b((v.z - mean) * rstd * gv.z + bv.z);
    o[3] = (short)f2b((v.w - mean) * rstd * gv.w + bv.w);
    xo[0] = (short)f2b(v.x);
    xo[1] = (short)f2b(v.y);
    xo[2] = (short)f2b(v.z);
    xo[3] = (short)f2b(v.w);
    *(sx4*)&xn[(size_t)row * 256 + l * 4] = o;
    *(sx4*)&xb[(size_t)row * 256 + l * 4] = xo;
    return;
  }
  const int tb = bid - 2048;
  const float* in; u16* out; int K, N, loc;
  if (tb < 192)      { in = ipw;  out = ipwT;  K = 256;  N = 768;  loc = tb; }
  else if (tb < 256) { in = outw; out = outwT; K = 256;  N = 256;  loc = tb - 192; }
  else if (tb < 512) { in = w1;   out = w1T;   K = 256;  N = 1024; loc = tb - 256; }
  else               { in = w2;   out = w2T;   K = 1024; N = 256;  loc = tb - 512; }
  const int ntx = N >> 5;
  const int by = (loc / ntx) << 5;  // k base
  const int bx = (loc % ntx) << 5;  // n base
  __shared__ float t[32][33];
  const int c = threadIdx.x & 31, r0 = threadIdx.x >> 5;
#pragma unroll
  for (int i = 0; i < 4; ++i)
    t[r0 + i * 8][c] = in[(size_t)(by + r0 + i * 8) * N + bx + c];
  __syncthreads();
#pragma unroll
  for (int i = 0; i < 4; ++i) {
    const int r = r0 + i * 8;
    out[(size_t)(bx + r) * K + by + c] = f2b(t[c][r]);
  }
}

// ---- GEMM v3: BK=64, double-buffered, XOR-swizzled LDS, XCD-grouped decode,
//      coalesced epilogue via LDS C-tile. (qkv projection)
template <int BM, int BN, int KD, int ND, int OP, int NGRP>
__global__ __launch_bounds__(256) void gemm3_k(const u16* __restrict__ A,
                                               const u16* __restrict__ Wt,
                                               const float* __restrict__ bias,
                                               const float* __restrict__ resid,
                                               void* __restrict__ outp) {
  constexpr int BK = 64;
  constexpr int WM = BM / 2, WN = BN / 2;
  constexpr int FM = WM / 16, FN = WN / 16;
  constexpr int NT = KD / BK;
  __shared__ __align__(16) char smem[(2 * BM + 2 * BN) * BK * 2];
  auto As = (u16(*)[BM][BK])smem;
  auto Bs = (u16(*)[BN][BK])(smem + 2 * BM * BK * 2);
  const int tid = threadIdx.x;
  const int id = blockIdx.x;
  const int bm = ((id & 7) + 8 * ((id >> 3) / NGRP)) * BM;
  const int bn = ((id >> 3) % NGRP) * BN;
  const int l = tid & 63, wid = tid >> 6;
  const int wm = wid >> 1, wn = wid & 1;
  const int lq = l & 15, lg = l >> 4;

  auto stage = [&](int buf, int k0) {
#pragma unroll
    for (int i = 0; i < (BM * BK) / 2048; ++i) {
      const int row = (tid >> 3) + 32 * i;
      const int c = (tid & 7) ^ (row & 7);
      gload16(&A[(size_t)(bm + row) * KD + k0 + c * 8], &As[buf][row][(tid & 7) * 8]);
    }
#pragma unroll
    for (int i = 0; i < (BN * BK) / 2048; ++i) {
      const int row = (tid >> 3) + 32 * i;
      const int c = (tid & 7) ^ (row & 7);
      gload16(&Wt[(size_t)(bn + row) * KD + k0 + c * 8], &Bs[buf][row][(tid & 7) * 8]);
    }
  };

  fx4 acc[FM][FN] = {};
  stage(0, 0);
  int cur = 0;
  for (int t = 0; t < NT; ++t) {
    __syncthreads();
    if (t + 1 < NT) stage(cur ^ 1, (t + 1) * BK);
#pragma unroll
    for (int kk = 0; kk < BK; kk += 32) {
      sx8 aF[FM], bF[FN];
#pragma unroll
      for (int m = 0; m < FM; ++m) {
        const int row = wm * WM + m * 16 + lq;
        const int c = ((kk >> 3) + lg) ^ (row & 7);
        aF[m] = *(const sx8*)&As[cur][row][c * 8];
      }
#pragma unroll
      for (int n = 0; n < FN; ++n) {
        const int row = wn * WN + n * 16 + lq;
        const int c = ((kk >> 3) + lg) ^ (row & 7);
        bF[n] = *(const sx8*)&Bs[cur][row][c * 8];
      }
#pragma unroll
      for (int m = 0; m < FM; ++m)
#pragma unroll
        for (int n = 0; n < FN; ++n) acc[m][n] = mfma32(aF[m], bF[n], acc[m][n]);
    }
    cur ^= 1;
  }

  __syncthreads();  // reuse smem as C tile
  {
    auto C = (u16(*)[BN + 8])smem;
#pragma unroll
    for (int m = 0; m < FM; ++m)
#pragma unroll
      for (int n = 0; n < FN; ++n) {
        const int col = wn * WN + n * 16 + lq;
        const float bv = bias[bn + col];
#pragma unroll
        for (int r = 0; r < 4; ++r) {
          float v = acc[m][n][r] + bv;
          C[wm * WM + m * 16 + lg * 4 + r][col] = f2b(v);
        }
      }
    __syncthreads();
    constexpr int CH = (BM * BN / 8) / 256;
#pragma unroll
    for (int i = 0; i < CH; ++i) {
      const int t = tid + i * 256;
      const int row = t / (BN / 8), c = t % (BN / 8);
      *(sx8*)&((u16*)outp)[(size_t)(bm + row) * ND + bn + c * 8] = *(const sx8*)&C[row][c * 8];
    }
  }
}

// ------- Fused out-proj + bias + x-residual(bf16) + LayerNorm2 -> yn bf16 ----
__global__ __launch_bounds__(256) void gemmln_k(const u16* __restrict__ A,
                                                const u16* __restrict__ Wt,
                                                const float* __restrict__ bias,
                                                const u16* __restrict__ xb,
                                                const float* __restrict__ g,
                                                const float* __restrict__ bv2,
                                                u16* __restrict__ yn) {
  __shared__ __align__(16) char smem[18944];
  auto As = (u16(*)[32])smem;               // [32][32]
  auto Bs = (u16(*)[32])(smem + 2048);      // [256][32]
  auto red = (float(*)[2][2])(smem + 18432);  // [32][2][2]
  auto Ys = (u16(*)[264])smem;              // [32][264] (reuses As+Bs)
  const int tid = threadIdx.x;
  const int bm = blockIdx.x * 32;
  const int l = tid & 63, wid = tid >> 6;
  const int wm = wid >> 1, wn = wid & 1;
  const int lq = l & 15, lg = l >> 4;
  const int sr = tid >> 2, sc = (tid & 3) << 3;
  fx4 acc[8] = {};
  for (int k0 = 0; k0 < 256; k0 += 32) {
    if (tid < 128) gload16(&A[(size_t)(bm + (tid >> 2)) * 256 + k0 + ((tid & 3) << 3)],
                           &As[tid >> 2][(tid & 3) << 3]);
#pragma unroll
    for (int i = 0; i < 4; ++i)
      gload16(&Wt[(size_t)(sr + i * 64) * 256 + k0 + sc], &Bs[sr + i * 64][sc]);
    __syncthreads();
    const sx8 aF = *(const sx8*)&As[wm * 16 + lq][8 * lg];
#pragma unroll
    for (int n = 0; n < 8; ++n) {
      const sx8 bF = *(const sx8*)&Bs[wn * 128 + n * 16 + lq][8 * lg];
      acc[n] = mfma32(aF, bF, acc[n]);
    }
    __syncthreads();
  }
  float vv[8][4];
  float s[4] = {}, q[4] = {};
#pragma unroll
  for (int n = 0; n < 8; ++n) {
    const int col = wn * 128 + n * 16 + lq;
    const float bb = bias[col];
#pragma unroll
    for (int r = 0; r < 4; ++r) {
      const int row = bm + wm * 16 + lg * 4 + r;
      const float v = acc[n][r] + bb + b2f(xb[(size_t)row * 256 + col]);
      vv[n][r] = v;
      s[r] += v;
      q[r] += v * v;
    }
  }
#pragma unroll
  for (int off = 1; off < 16; off <<= 1) {
#pragma unroll
    for (int r = 0; r < 4; ++r) {
      s[r] += __shfl_xor(s[r], off);
      q[r] += __shfl_xor(q[r], off);
    }
  }
  if (lq == 0) {
#pragma unroll
    for (int r = 0; r < 4; ++r) {
      red[wm * 16 + lg * 4 + r][wn][0] = s[r];
      red[wm * 16 + lg * 4 + r][wn][1] = q[r];
    }
  }
  __syncthreads();
  float mean4[4], rs4[4];
#pragma unroll
  for (int r = 0; r < 4; ++r) {
    const int rr = wm * 16 + lg * 4 + r;
    const float st = red[rr][0][0] + red[rr][1][0];
    const float qt = red[rr][0][1] + red[rr][1][1];
    mean4[r] = st * (1.0f / 256.0f);
    const float var = qt * (1.0f / 256.0f) - mean4[r] * mean4[r];
    rs4[r] = rsqrtf(var + 1e-5f);
  }
  __syncthreads();
#pragma unroll
  for (int n = 0; n < 8; ++n) {
    const int col = wn * 128 + n * 16 + lq;
    const float gc = g[col], bc = bv2[col];
#pragma unroll
    for (int r = 0; r < 4; ++r)
      Ys[wm * 16 + lg * 4 + r][col] = f2b((vv[n][r] - mean4[r]) * rs4[r] * gc + bc);
  }
  __syncthreads();
#pragma unroll
  for (int i = 0; i < 4; ++i) {
    const int t = tid + i * 256;
    const int row = t >> 5, c = t & 31;
    *(sx8*)&yn[(size_t)(bm + row) * 256 + c * 8] = *(const sx8*)&Ys[row][c * 8];
  }
}

// ---------------- Banded flash attention, 128-q tiles, one-pass softmax ------
__global__ __launch_bounds__(512) void attn_k(const u16* __restrict__ qkv,
                                              u16* __restrict__ o) {
  __shared__ u16 Qs[128][32];
  __shared__ u16 Ks[256][32];
  __shared__ u16 Vs[32][264];  // transposed: Vs[d][key]
  const int blk = blockIdx.x;
  const int tile = blk & 15;
  const int bh = blk >> 4;
  const int h = bh & 7;
  const int b = bh >> 3;
  const int q0 = tile << 7;
  const int kstart = max(0, q0 - 64);
  const int kend = min(T_SEQ, q0 + 192);
  const int nk = kend - kstart;
  const int tid = threadIdx.x;
  const float scale = 0.17677669529663687f;  // 1/sqrt(32)

  {
    const int r = tid >> 2, c8 = (tid & 3) << 3;
    gload16(&qkv[(size_t)(b * T_SEQ + q0 + r) * 768 + h * 32 + c8], &Qs[r][c8]);
  }
  for (int r0 = 0; r0 < nk; r0 += 128) {
    const int r = r0 + (tid >> 2);
    if (r < nk) {
      const int c8 = (tid & 3) << 3;
      gload16(&qkv[(size_t)(b * T_SEQ + kstart + r) * 768 + 256 + h * 32 + c8], &Ks[r][c8]);
    }
  }
  for (int e = tid * 4; e < nk * 32; e += 2048) {
    const int r = e >> 5, c = e & 31;
    sx4 v = *(const sx4*)&qkv[(size_t)(b * T_SEQ + kstart + r) * 768 + 512 + h * 32 + c];
    Vs[c + 0][r] = v[0];
    Vs[c + 1][r] = v[1];
    Vs[c + 2][r] = v[2];
    Vs[c + 3][r] = v[3];
  }
  __syncthreads();

  const int w = tid >> 6, l = tid & 63;
  const int lq = l & 15, lg = l >> 4;
  const int qw0 = q0 + w * 16;
  const int iq = qw0 + lq;
  const sx8 qB = *(const sx8*)&Qs[w * 16 + lq][8 * lg];
  float lsum = 0.0f;
  fx4 acc0 = {0.f, 0.f, 0.f, 0.f}, acc1 = {0.f, 0.f, 0.f, 0.f};
  const int rt0 = max(0, qw0 - 64 - kstart) >> 4;
  const int rt1 = (min(kend, qw0 + 80) - kstart) >> 4;
  for (int rt = rt0; rt < rt1; ++rt) {
    const int kb = kstart + (rt << 4);
    const sx8 kA = *(const sx8*)&Ks[(rt << 4) + lq][8 * lg];
    fx4 zero = {0.f, 0.f, 0.f, 0.f};
    fx4 sc = mfma32(kA, qB, zero);
    sx4 pB;
#pragma unroll
    for (int r = 0; r < 4; ++r) {
      const int dd = kb + 4 * lg + r - iq;
      const float sv = (dd >= -64 && dd <= 64) ? fminf(sc[r] * scale, 30.0f) : -100.0f;
      const float p = __expf(sv);
      lsum += p;
      pB[r] = (short)f2b(p);
    }
    const sx4 vA0 = *(const sx4*)&Vs[lq][(rt << 4) + 4 * lg];
    const sx4 vA1 = *(const sx4*)&Vs[16 + lq][(rt << 4) + 4 * lg];
    acc0 = mfma16(vA0, pB, acc0);
    acc1 = mfma16(vA1, pB, acc1);
  }
  lsum += __shfl_xor(lsum, 16);
  lsum += __shfl_xor(lsum, 32);
  const float rl = 1.0f / lsum;

  __syncthreads();
  auto Os = (u16(*)[32])Qs;
#pragma unroll
  for (int r = 0; r < 4; ++r) {
    Os[w * 16 + lq][4 * lg + r] = f2b(acc0[r] * rl);
    Os[w * 16 + lq][16 + 4 * lg + r] = f2b(acc1[r] * rl);
  }
  __syncthreads();
  {
    const int row = tid >> 2, c = tid & 3;
    *(sx8*)&o[(size_t)(b * T_SEQ + q0 + row) * 256 + h * 32 + c * 8] =
        *(const sx8*)&Os[row][c * 8];
  }
}

// ---------------- Fused MLP: out = x + (GELU(yn@w1+b1)) @ w2 + b2 -----------
// 32 rows/block, 16 chunks of 64 FF dims; hh never materialized.
// Weight chunks double-buffered via global_load_lds; mid-chunk barrier is
// lgkm-only (raw s_barrier) so the weight prefetch stays in flight.
__global__ __launch_bounds__(256) void mlp_k(const u16* __restrict__ yn,
                                             const u16* __restrict__ w1T,
                                             const u16* __restrict__ w2T,
                                             const float* __restrict__ b1,
                                             const float* __restrict__ b2,
                                             const float* __restrict__ x,
                                             float* __restrict__ out) {
  __shared__ __align__(16) char smem[151552];
  auto As = (u16(*)[32][64])smem;             // [4][32][64] yn (swizzled)
  auto Hs = (u16(*)[64])(smem + 16384);       // [32][64] h (swizzled)
  const int tid = threadIdx.x;
  const int bm = blockIdx.x * 32;
  const int l = tid & 63, wid = tid >> 6;
  const int lq = l & 15, lg = l >> 4;

  // stage yn strip: 4 slabs x [32][64]
#pragma unroll
  for (int s = 0; s < 4; ++s) {
    const int row = tid >> 3, ch = tid & 7;
    gload16(&yn[(size_t)(bm + row) * 256 + s * 64 + ((ch ^ (row & 7)) << 3)],
            &As[s][row][ch << 3]);
  }
  auto stage_w = [&](int b, int c) {
    auto W1 = (u16(*)[64][64])(smem + 20480 + b * 32768);  // [4][64][64]
    auto W2 = (u16(*)[64])(smem + 86016 + b * 32768);      // [256][64]
#pragma unroll
    for (int j = 0; j < 8; ++j) {
      const int p = tid + j * 256;
      const int s = p >> 9, w = p & 511, row = w >> 3, ch = w & 7;
      gload16(&w1T[(size_t)(c * 64 + row) * 256 + s * 64 + ((ch ^ (row & 7)) << 3)],
              &W1[s][row][ch << 3]);
    }
#pragma unroll
    for (int j = 0; j < 8; ++j) {
      const int p = tid + j * 256;
      const int row = p >> 3, ch = p & 7;
      gload16(&w2T[(size_t)row * 1024 + c * 64 + ((ch ^ (row & 7)) << 3)],
              &W2[row][ch << 3]);
    }
  };

  fx4 acc[2][4] = {};
  stage_w(0, 0);
  __syncthreads();  // yn + chunk0 ready
  int cur = 0;
  for (int c = 0; c < 16; ++c) {
    if (c) __syncthreads();  // stage(c) landed (vmcnt0); Hs safe to overwrite
    if (c + 1 < 16) stage_w(cur ^ 1, c + 1);
    auto W1 = (u16(*)[64][64])(smem + 20480 + cur * 32768);
    auto W2 = (u16(*)[64])(smem + 86016 + cur * 32768);
    const int rfw = wid * 16 + lq;  // ff col (0..63) this lane computes
    // ---- ff1: h = yn @ w1_chunk ----
    fx4 hacc0 = {0.f, 0.f, 0.f, 0.f}, hacc1 = {0.f, 0.f, 0.f, 0.f};
#pragma unroll
    for (int s = 0; s < 4; ++s)
#pragma unroll
      for (int kk = 0; kk < 2; ++kk) {
        const int cc = kk * 4 + lg;
        const sx8 bF = *(const sx8*)&W1[s][rfw][(cc ^ (rfw & 7)) << 3];
        const sx8 aF0 = *(const sx8*)&As[s][lq][(cc ^ (lq & 7)) << 3];
        const sx8 aF1 = *(const sx8*)&As[s][16 + lq][(cc ^ (lq & 7)) << 3];
        hacc0 = mfma32(aF0, bF, hacc0);
        hacc1 = mfma32(aF1, bF, hacc1);
      }
    // ---- GELU + write h to LDS (swizzled) ----
    const float bb1 = b1[c * 64 + rfw];
#pragma unroll
    for (int r = 0; r < 4; ++r) {
      {
        float v = hacc0[r] + bb1;
        v = 0.5f * v * (1.0f + erff(v * 0.70710678118654752f));
        const int row = 4 * lg + r;
        Hs[row][(((rfw >> 3) ^ (row & 7)) << 3) | (rfw & 7)] = f2b(v);
      }
      {
        float v = hacc1[r] + bb1;
        v = 0.5f * v * (1.0f + erff(v * 0.70710678118654752f));
        const int row = 16 + 4 * lg + r;
        Hs[row][(((rfw >> 3) ^ (row & 7)) << 3) | (rfw & 7)] = f2b(v);
      }
    }
    // h visible to all waves; do NOT drain vmcnt (weight prefetch in flight)
    asm volatile("s_waitcnt lgkmcnt(0)\n\ts_barrier" ::: "memory");
    // ---- ff2: acc += h @ w2_chunk ----
#pragma unroll
    for (int kk = 0; kk < 2; ++kk) {
      const int cc = kk * 4 + lg;
      const sx8 aH0 = *(const sx8*)&Hs[lq][(cc ^ (lq & 7)) << 3];
      const sx8 aH1 = *(const sx8*)&Hs[16 + lq][(cc ^ (lq & 7)) << 3];
#pragma unroll
      for (int n = 0; n < 4; ++n) {
        const int rw = wid * 64 + n * 16 + lq;
        const sx8 bW = *(const sx8*)&W2[rw][(cc ^ (rw & 7)) << 3];
        acc[0][n] = mfma32(aH0, bW, acc[0][n]);
        acc[1][n] = mfma32(aH1, bW, acc[1][n]);
      }
    }
    cur ^= 1;
  }

  // ---- epilogue: +b2, +x, coalesced f32 stores via LDS C-tile ----
  __syncthreads();
  auto Cs = (float(*)[264])smem;
#pragma unroll
  for (int n = 0; n < 4; ++n) {
    const int col = wid * 64 + n * 16 + lq;
    const float bb = b2[col];
#pragma unroll
    for (int m = 0; m < 2; ++m)
#pragma unroll
      for (int r = 0; r < 4; ++r)
        Cs[m * 16 + 4 * lg + r][col] = acc[m][n][r] + bb;
  }
  __syncthreads();
#pragma unroll
  for (int j = 0; j < 8; ++j) {
    const int p = tid + j * 256;
    const int row = p >> 6, c4 = (p & 63) << 2;
    fx4 v = *(const fx4*)&Cs[row][c4];
    v += *(const fx4*)&x[(size_t)(bm + row) * 256 + c4];
    *(fx4*)&out[(size_t)(bm + row) * 256 + c4] = v;
  }
}

extern "C" void kernel_launch(void* const* d_in, const int* in_sizes, int n_in,
                              void* d_out, int out_size, void* d_ws, size_t ws_size,
                              hipStream_t stream) {
  const float* x    = (const float*)d_in[0];
  const float* ln1g = (const float*)d_in[1];
  const float* ln1b = (const float*)d_in[2];
  const float* ipw  = (const float*)d_in[3];
  const float* ipb  = (const float*)d_in[4];
  const float* outw = (const float*)d_in[5];
  const float* outb = (const float*)d_in[6];
  const float* ln2g = (const float*)d_in[7];
  const float* ln2b = (const float*)d_in[8];
  const float* w1   = (const float*)d_in[9];
  const float* b1   = (const float*)d_in[10];
  const float* w2   = (const float*)d_in[11];
  const float* b2   = (const float*)d_in[12];

  char* ws = (char*)d_ws;
  u16*   xn   = (u16*)(ws);                          // 4 MB  bf16 [8192][256]
  u16*   qkvb = (u16*)(ws + (4ull << 20));           // 12 MB bf16 [8192][768]
  u16*   o    = (u16*)(ws + (16ull << 20));          // 4 MB  bf16 [8192][256]
  u16*   yn   = (u16*)(ws + (20ull << 20));          // 4 MB  bf16 [8192][256]
  u16*   xb   = (u16*)(ws + (24ull << 20));          // 4 MB  bf16 [8192][256]
  u16*   ipwT = (u16*)(ws + (28ull << 20));          // 384 KB bf16 [768][256]
  u16*   outwT= (u16*)(ws + (28ull << 20) + (512ull << 10));   // 128 KB [256][256]
  u16*   w1T  = (u16*)(ws + (29ull << 20));          // 512 KB bf16 [1024][256]
  u16*   w2T  = (u16*)(ws + (29ull << 20) + (512ull << 10));   // 512 KB [256][1024]

  prep_k<<<2816, 256, 0, stream>>>(x, ln1g, ln1b, xn, xb, ipw, outw, w1, w2,
                                   ipwT, outwT, w1T, w2T);
  gemm3_k<128, 128, 256, 768, 0, 6><<<384, 256, 0, stream>>>(xn, ipwT, ipb, nullptr, qkvb);
  attn_k<<<512, 512, 0, stream>>>(qkvb, o);
  gemmln_k<<<256, 256, 0, stream>>>(o, outwT, outb, xb, ln2g, ln2b, yn);
  mlp_k<<<256, 256, 0, stream>>>(yn, w1T, w2T, b1, b2, x, (float*)d_out);
}

// Round 9
// 59.148 us; speedup vs baseline: 1.1926x; 1.1926x over previous
//
#include <hip/hip_runtime.h>
#include <math.h>

#define T_SEQ 2048

typedef float  fx4 __attribute__((ext_vector_type(4)));
typedef short  sx4 __attribute__((ext_vector_type(4)));
typedef short  sx8 __attribute__((ext_vector_type(8)));
typedef unsigned short u16;

static __device__ __forceinline__ u16 f2b(float f) {
  unsigned u = __builtin_bit_cast(unsigned, f);
  u += 0x7fffu + ((u >> 16) & 1u);   // RNE
  return (u16)(u >> 16);
}
static __device__ __forceinline__ float b2f(u16 v) {
  unsigned u = ((unsigned)v) << 16;
  return __builtin_bit_cast(float, u);
}

static __device__ __forceinline__ fx4 mfma16(sx4 a, sx4 b, fx4 c) {
  return __builtin_amdgcn_mfma_f32_16x16x16bf16_1k(a, b, c, 0, 0, 0);
}
static __device__ __forceinline__ fx4 mfma32(sx8 a, sx8 b, fx4 c) {
  return __builtin_amdgcn_mfma_f32_16x16x32_bf16(a, b, c, 0, 0, 0);
}

static __device__ __forceinline__ void gload16(const void* g, void* l) {
  __builtin_amdgcn_global_load_lds(
      (const __attribute__((address_space(1))) unsigned*)g,
      (__attribute__((address_space(3))) unsigned*)l, 16, 0, 0);
}

// -- prep: LN1 + x->bf16 (blocks 0..2047), weight transposes (2048..2815) ----
__global__ __launch_bounds__(256) void prep_k(
    const float* __restrict__ x, const float* __restrict__ g1,
    const float* __restrict__ b1, u16* __restrict__ xn, u16* __restrict__ xb,
    const float* __restrict__ ipw, const float* __restrict__ outw,
    const float* __restrict__ w1, const float* __restrict__ w2,
    u16* __restrict__ ipwT, u16* __restrict__ outwT,
    u16* __restrict__ w1T, u16* __restrict__ w2T) {
  const int bid = blockIdx.x;
  if (bid < 2048) {
    const int row = bid * 4 + (threadIdx.x >> 6);
    const int l = threadIdx.x & 63;
    fx4 v = *(const fx4*)&x[(size_t)row * 256 + l * 4];
    float s = v.x + v.y + v.z + v.w;
    float q = v.x * v.x + v.y * v.y + v.z * v.z + v.w * v.w;
#pragma unroll
    for (int off = 1; off < 64; off <<= 1) {
      s += __shfl_xor(s, off);
      q += __shfl_xor(q, off);
    }
    const float mean = s * (1.0f / 256.0f);
    const float var = q * (1.0f / 256.0f) - mean * mean;
    const float rstd = rsqrtf(var + 1e-5f);
    fx4 gv = *(const fx4*)&g1[l * 4];
    fx4 bv = *(const fx4*)&b1[l * 4];
    sx4 o, xo;
    o[0] = (short)f2b((v.x - mean) * rstd * gv.x + bv.x);
    o[1] = (short)f2b((v.y - mean) * rstd * gv.y + bv.y);
    o[2] = (short)f2b((v.z - mean) * rstd * gv.z + bv.z);
    o[3] = (short)f2b((v.w - mean) * rstd * gv.w + bv.w);
    xo[0] = (short)f2b(v.x);
    xo[1] = (short)f2b(v.y);
    xo[2] = (short)f2b(v.z);
    xo[3] = (short)f2b(v.w);
    *(sx4*)&xn[(size_t)row * 256 + l * 4] = o;
    *(sx4*)&xb[(size_t)row * 256 + l * 4] = xo;
    return;
  }
  const int tb = bid - 2048;
  const float* in; u16* out; int K, N, loc;
  if (tb < 192)      { in = ipw;  out = ipwT;  K = 256;  N = 768;  loc = tb; }
  else if (tb < 256) { in = outw; out = outwT; K = 256;  N = 256;  loc = tb - 192; }
  else if (tb < 512) { in = w1;   out = w1T;   K = 256;  N = 1024; loc = tb - 256; }
  else               { in = w2;   out = w2T;   K = 1024; N = 256;  loc = tb - 512; }
  const int ntx = N >> 5;
  const int by = (loc / ntx) << 5;  // k base
  const int bx = (loc % ntx) << 5;  // n base
  __shared__ float t[32][33];
  const int c = threadIdx.x & 31, r0 = threadIdx.x >> 5;
#pragma unroll
  for (int i = 0; i < 4; ++i)
    t[r0 + i * 8][c] = in[(size_t)(by + r0 + i * 8) * N + bx + c];
  __syncthreads();
#pragma unroll
  for (int i = 0; i < 4; ++i) {
    const int r = r0 + i * 8;
    out[(size_t)(bx + r) * K + by + c] = f2b(t[c][r]);
  }
}

// ---- GEMM v5: 512 threads (8 waves, 2x4), BK=64 dbuf, XOR-swizzled LDS,
//      XCD-grouped decode, coalesced epilogue via LDS C-tile.
// OP: 0 = store bf16, 1 = +resid store f32, 2 = exact-GELU store bf16
template <int BM, int BN, int KD, int ND, int OP, int NGRP>
__global__ __launch_bounds__(512) void gemm5_k(const u16* __restrict__ A,
                                               const u16* __restrict__ Wt,
                                               const float* __restrict__ bias,
                                               const float* __restrict__ resid,
                                               void* __restrict__ outp) {
  constexpr int BK = 64;
  constexpr int WTM = BM / 2, WTN = BN / 4;
  constexpr int FM = WTM / 16, FN = WTN / 16;
  constexpr int NT = KD / BK;
  __shared__ __align__(16) char smem[(2 * BM + 2 * BN) * BK * 2];
  auto As = (u16(*)[BM][BK])smem;
  auto Bs = (u16(*)[BN][BK])(smem + 2 * BM * BK * 2);
  const int tid = threadIdx.x;
  const int id = blockIdx.x;
  const int bm = ((id & 7) + 8 * ((id >> 3) / NGRP)) * BM;
  const int bn = ((id >> 3) % NGRP) * BN;
  const int l = tid & 63, wid = tid >> 6;
  const int wr = wid >> 2, wc = wid & 3;
  const int lq = l & 15, lg = l >> 4;

  auto stage = [&](int buf, int k0) {
#pragma unroll
    for (int i = 0; i < BM / 64; ++i) {
      const int p = tid + i * 512;
      const int row = p >> 3, ch = p & 7;
      gload16(&A[(size_t)(bm + row) * KD + k0 + ((ch ^ (row & 7)) << 3)],
              &As[buf][row][ch << 3]);
    }
#pragma unroll
    for (int i = 0; i < BN / 64; ++i) {
      const int p = tid + i * 512;
      const int row = p >> 3, ch = p & 7;
      gload16(&Wt[(size_t)(bn + row) * KD + k0 + ((ch ^ (row & 7)) << 3)],
              &Bs[buf][row][ch << 3]);
    }
  };

  fx4 acc[FM][FN] = {};
  stage(0, 0);
  int cur = 0;
  for (int t = 0; t < NT; ++t) {
    __syncthreads();
    if (t + 1 < NT) stage(cur ^ 1, (t + 1) * BK);
#pragma unroll
    for (int kk = 0; kk < BK; kk += 32) {
      sx8 aF[FM], bF[FN];
#pragma unroll
      for (int m = 0; m < FM; ++m) {
        const int row = wr * WTM + m * 16 + lq;
        aF[m] = *(const sx8*)&As[cur][row][((((kk >> 3) + lg) ^ (row & 7)) << 3)];
      }
#pragma unroll
      for (int n = 0; n < FN; ++n) {
        const int row = wc * WTN + n * 16 + lq;
        bF[n] = *(const sx8*)&Bs[cur][row][((((kk >> 3) + lg) ^ (row & 7)) << 3)];
      }
#pragma unroll
      for (int m = 0; m < FM; ++m)
#pragma unroll
        for (int n = 0; n < FN; ++n) acc[m][n] = mfma32(aF[m], bF[n], acc[m][n]);
    }
    cur ^= 1;
  }

  __syncthreads();  // all LDS reads done; reuse smem as C tile
  if (OP == 1) {
    auto C = (float(*)[BN + 8])smem;
#pragma unroll
    for (int m = 0; m < FM; ++m)
#pragma unroll
      for (int n = 0; n < FN; ++n) {
        const int col = wc * WTN + n * 16 + lq;
        const float bv = bias[bn + col];
#pragma unroll
        for (int r = 0; r < 4; ++r)
          C[wr * WTM + m * 16 + lg * 4 + r][col] = acc[m][n][r] + bv;
      }
    __syncthreads();
    constexpr int CH = (BM * BN / 4) / 512;
#pragma unroll
    for (int i = 0; i < CH; ++i) {
      const int t = tid + i * 512;
      const int row = t / (BN / 4), c = t % (BN / 4);
      fx4 v = *(const fx4*)&C[row][c * 4];
      v += *(const fx4*)&resid[(size_t)(bm + row) * ND + bn + c * 4];
      *(fx4*)&((float*)outp)[(size_t)(bm + row) * ND + bn + c * 4] = v;
    }
  } else {
    auto C = (u16(*)[BN + 8])smem;
#pragma unroll
    for (int m = 0; m < FM; ++m)
#pragma unroll
      for (int n = 0; n < FN; ++n) {
        const int col = wc * WTN + n * 16 + lq;
        const float bv = bias[bn + col];
#pragma unroll
        for (int r = 0; r < 4; ++r) {
          float v = acc[m][n][r] + bv;
          if (OP == 2) v = 0.5f * v * (1.0f + erff(v * 0.70710678118654752f));
          C[wr * WTM + m * 16 + lg * 4 + r][col] = f2b(v);
        }
      }
    __syncthreads();
    constexpr int CH = (BM * BN / 8) / 512;
#pragma unroll
    for (int i = 0; i < CH; ++i) {
      const int t = tid + i * 512;
      const int row = t / (BN / 8), c = t % (BN / 8);
      *(sx8*)&((u16*)outp)[(size_t)(bm + row) * ND + bn + c * 8] = *(const sx8*)&C[row][c * 8];
    }
  }
}

// ------- Fused out-proj + bias + x-residual(bf16) + LayerNorm2 -> yn bf16 ----
// 512 threads, BK=64 double-buffered, swizzled LDS.
__global__ __launch_bounds__(512) void gemmln_k(const u16* __restrict__ A,
                                                const u16* __restrict__ Wt,
                                                const float* __restrict__ bias,
                                                const u16* __restrict__ xb,
                                                const float* __restrict__ g,
                                                const float* __restrict__ bv2,
                                                u16* __restrict__ yn) {
  __shared__ __align__(16) char smem[74752];
  auto As = (u16(*)[32][64])smem;              // [2][32][64]
  auto Bs = (u16(*)[256][64])(smem + 8192);    // [2][256][64]
  auto red = (float(*)[4][2])(smem + 73728);   // [32][4][2]
  auto Ys = (u16(*)[264])smem;                 // [32][264] (aliases As/Bs)
  const int tid = threadIdx.x;
  const int bm = blockIdx.x * 32;
  const int l = tid & 63, wid = tid >> 6;
  const int wr = wid >> 2, wc = wid & 3;
  const int lq = l & 15, lg = l >> 4;

  auto stage = [&](int buf, int k0) {
    if (tid < 256) {
      const int row = tid >> 3, ch = tid & 7;
      gload16(&A[(size_t)(bm + row) * 256 + k0 + ((ch ^ (row & 7)) << 3)],
              &As[buf][row][ch << 3]);
    }
#pragma unroll
    for (int i = 0; i < 4; ++i) {
      const int p = tid + i * 512;
      const int row = p >> 3, ch = p & 7;
      gload16(&Wt[(size_t)row * 256 + k0 + ((ch ^ (row & 7)) << 3)],
              &Bs[buf][row][ch << 3]);
    }
  };

  fx4 acc[4] = {};
  stage(0, 0);
  int cur = 0;
  for (int t = 0; t < 4; ++t) {
    __syncthreads();
    if (t + 1 < 4) stage(cur ^ 1, (t + 1) * 64);
#pragma unroll
    for (int kk = 0; kk < 64; kk += 32) {
      const int arow = wr * 16 + lq;
      const sx8 aF = *(const sx8*)&As[cur][arow][((((kk >> 3) + lg) ^ (arow & 7)) << 3)];
#pragma unroll
      for (int n = 0; n < 4; ++n) {
        const int brow = wc * 64 + n * 16 + lq;
        const sx8 bF = *(const sx8*)&Bs[cur][brow][((((kk >> 3) + lg) ^ (brow & 7)) << 3)];
        acc[n] = mfma32(aF, bF, acc[n]);
      }
    }
    cur ^= 1;
  }

  float vv[4][4];
  float s[4] = {}, q[4] = {};
#pragma unroll
  for (int n = 0; n < 4; ++n) {
    const int col = wc * 64 + n * 16 + lq;
    const float bb = bias[col];
#pragma unroll
    for (int r = 0; r < 4; ++r) {
      const int row = bm + wr * 16 + lg * 4 + r;
      const float v = acc[n][r] + bb + b2f(xb[(size_t)row * 256 + col]);
      vv[n][r] = v;
      s[r] += v;
      q[r] += v * v;
    }
  }
#pragma unroll
  for (int off = 1; off < 16; off <<= 1) {
#pragma unroll
    for (int r = 0; r < 4; ++r) {
      s[r] += __shfl_xor(s[r], off);
      q[r] += __shfl_xor(q[r], off);
    }
  }
  __syncthreads();  // all fragment reads done (also orders red writes)
  if (lq == 0) {
#pragma unroll
    for (int r = 0; r < 4; ++r) {
      red[wr * 16 + lg * 4 + r][wc][0] = s[r];
      red[wr * 16 + lg * 4 + r][wc][1] = q[r];
    }
  }
  __syncthreads();
  float mean4[4], rs4[4];
#pragma unroll
  for (int r = 0; r < 4; ++r) {
    const int rr = wr * 16 + lg * 4 + r;
    const float st = red[rr][0][0] + red[rr][1][0] + red[rr][2][0] + red[rr][3][0];
    const float qt = red[rr][0][1] + red[rr][1][1] + red[rr][2][1] + red[rr][3][1];
    mean4[r] = st * (1.0f / 256.0f);
    const float var = qt * (1.0f / 256.0f) - mean4[r] * mean4[r];
    rs4[r] = rsqrtf(var + 1e-5f);
  }
  __syncthreads();  // safe to overwrite As/Bs region with Ys
#pragma unroll
  for (int n = 0; n < 4; ++n) {
    const int col = wc * 64 + n * 16 + lq;
    const float gc = g[col], bc = bv2[col];
#pragma unroll
    for (int r = 0; r < 4; ++r)
      Ys[wr * 16 + lg * 4 + r][col] = f2b((vv[n][r] - mean4[r]) * rs4[r] * gc + bc);
  }
  __syncthreads();
#pragma unroll
  for (int i = 0; i < 2; ++i) {
    const int t = tid + i * 512;
    const int row = t >> 5, c = t & 31;
    *(sx8*)&yn[(size_t)(bm + row) * 256 + c * 8] = *(const sx8*)&Ys[row][c * 8];
  }
}

// ---------------- Banded flash attention, 128-q tiles, one-pass softmax ------
__global__ __launch_bounds__(512) void attn_k(const u16* __restrict__ qkv,
                                              u16* __restrict__ o) {
  __shared__ u16 Qs[128][32];
  __shared__ u16 Ks[256][32];
  __shared__ u16 Vs[32][264];  // transposed: Vs[d][key]
  const int blk = blockIdx.x;
  const int tile = blk & 15;
  const int bh = blk >> 4;
  const int h = bh & 7;
  const int b = bh >> 3;
  const int q0 = tile << 7;
  const int kstart = max(0, q0 - 64);
  const int kend = min(T_SEQ, q0 + 192);
  const int nk = kend - kstart;
  const int tid = threadIdx.x;
  const float scale = 0.17677669529663687f;  // 1/sqrt(32)

  {
    const int r = tid >> 2, c8 = (tid & 3) << 3;
    gload16(&qkv[(size_t)(b * T_SEQ + q0 + r) * 768 + h * 32 + c8], &Qs[r][c8]);
  }
  for (int r0 = 0; r0 < nk; r0 += 128) {
    const int r = r0 + (tid >> 2);
    if (r < nk) {
      const int c8 = (tid & 3) << 3;
      gload16(&qkv[(size_t)(b * T_SEQ + kstart + r) * 768 + 256 + h * 32 + c8], &Ks[r][c8]);
    }
  }
  for (int e = tid * 4; e < nk * 32; e += 2048) {
    const int r = e >> 5, c = e & 31;
    sx4 v = *(const sx4*)&qkv[(size_t)(b * T_SEQ + kstart + r) * 768 + 512 + h * 32 + c];
    Vs[c + 0][r] = v[0];
    Vs[c + 1][r] = v[1];
    Vs[c + 2][r] = v[2];
    Vs[c + 3][r] = v[3];
  }
  __syncthreads();

  const int w = tid >> 6, l = tid & 63;
  const int lq = l & 15, lg = l >> 4;
  const int qw0 = q0 + w * 16;
  const int iq = qw0 + lq;
  const sx8 qB = *(const sx8*)&Qs[w * 16 + lq][8 * lg];
  float lsum = 0.0f;
  fx4 acc0 = {0.f, 0.f, 0.f, 0.f}, acc1 = {0.f, 0.f, 0.f, 0.f};
  const int rt0 = max(0, qw0 - 64 - kstart) >> 4;
  const int rt1 = (min(kend, qw0 + 80) - kstart) >> 4;
  for (int rt = rt0; rt < rt1; ++rt) {
    const int kb = kstart + (rt << 4);
    const sx8 kA = *(const sx8*)&Ks[(rt << 4) + lq][8 * lg];
    fx4 zero = {0.f, 0.f, 0.f, 0.f};
    fx4 sc = mfma32(kA, qB, zero);
    sx4 pB;
#pragma unroll
    for (int r = 0; r < 4; ++r) {
      const int dd = kb + 4 * lg + r - iq;
      const float sv = (dd >= -64 && dd <= 64) ? fminf(sc[r] * scale, 30.0f) : -100.0f;
      const float p = __expf(sv);
      lsum += p;
      pB[r] = (short)f2b(p);
    }
    const sx4 vA0 = *(const sx4*)&Vs[lq][(rt << 4) + 4 * lg];
    const sx4 vA1 = *(const sx4*)&Vs[16 + lq][(rt << 4) + 4 * lg];
    acc0 = mfma16(vA0, pB, acc0);
    acc1 = mfma16(vA1, pB, acc1);
  }
  lsum += __shfl_xor(lsum, 16);
  lsum += __shfl_xor(lsum, 32);
  const float rl = 1.0f / lsum;

  __syncthreads();
  auto Os = (u16(*)[32])Qs;
#pragma unroll
  for (int r = 0; r < 4; ++r) {
    Os[w * 16 + lq][4 * lg + r] = f2b(acc0[r] * rl);
    Os[w * 16 + lq][16 + 4 * lg + r] = f2b(acc1[r] * rl);
  }
  __syncthreads();
  {
    const int row = tid >> 2, c = tid & 3;
    *(sx8*)&o[(size_t)(b * T_SEQ + q0 + row) * 256 + h * 32 + c * 8] =
        *(const sx8*)&Os[row][c * 8];
  }
}

extern "C" void kernel_launch(void* const* d_in, const int* in_sizes, int n_in,
                              void* d_out, int out_size, void* d_ws, size_t ws_size,
                              hipStream_t stream) {
  const float* x    = (const float*)d_in[0];
  const float* ln1g = (const float*)d_in[1];
  const float* ln1b = (const float*)d_in[2];
  const float* ipw  = (const float*)d_in[3];
  const float* ipb  = (const float*)d_in[4];
  const float* outw = (const float*)d_in[5];
  const float* outb = (const float*)d_in[6];
  const float* ln2g = (const float*)d_in[7];
  const float* ln2b = (const float*)d_in[8];
  const float* w1   = (const float*)d_in[9];
  const float* b1   = (const float*)d_in[10];
  const float* w2   = (const float*)d_in[11];
  const float* b2   = (const float*)d_in[12];

  char* ws = (char*)d_ws;
  u16*   xn   = (u16*)(ws);                          // 4 MB  bf16 [8192][256]
  u16*   qkvb = (u16*)(ws + (4ull << 20));           // 12 MB bf16 [8192][768]
  u16*   o    = (u16*)(ws + (16ull << 20));          // 4 MB  bf16 [8192][256]
  u16*   yn   = (u16*)(ws + (20ull << 20));          // 4 MB  bf16 [8192][256]
  u16*   hh   = (u16*)(ws + (24ull << 20));          // 16 MB bf16 [8192][1024]
  u16*   xb   = (u16*)(ws + (40ull << 20));          // 4 MB  bf16 [8192][256]
  u16*   ipwT = (u16*)(ws + (44ull << 20));          // 384 KB bf16 [768][256]
  u16*   outwT= (u16*)(ws + (44ull << 20) + (512ull << 10));   // 128 KB [256][256]
  u16*   w1T  = (u16*)(ws + (45ull << 20));          // 512 KB bf16 [1024][256]
  u16*   w2T  = (u16*)(ws + (45ull << 20) + (512ull << 10));   // 512 KB [256][1024]

  prep_k<<<2816, 256, 0, stream>>>(x, ln1g, ln1b, xn, xb, ipw, outw, w1, w2,
                                   ipwT, outwT, w1T, w2T);
  gemm5_k<128, 128, 256, 768, 0, 6><<<384, 512, 0, stream>>>(xn, ipwT, ipb, nullptr, qkvb);
  attn_k<<<512, 512, 0, stream>>>(qkvb, o);
  gemmln_k<<<256, 512, 0, stream>>>(o, outwT, outb, xb, ln2g, ln2b, yn);
  gemm5_k<128, 128, 256, 1024, 2, 8><<<512, 512, 0, stream>>>(yn, w1T, b1, nullptr, hh);
  gemm5_k<64, 128, 1024, 256, 1, 2><<<256, 512, 0, stream>>>(hh, w2T, b2, x, (float*)d_out);
}